// Round 1
// baseline (543.397 us; speedup 1.0000x reference)
//
#include <hip/hip_runtime.h>

// ---------------------------------------------------------------------------
// T5-style self-attention, MI355X (gfx950), fp16 MFMA internal precision.
// B=2, S=2048, H=16, DK=64, D_MODEL=1024.
// ---------------------------------------------------------------------------

typedef _Float16 f16_t;
typedef _Float16 f16x8 __attribute__((ext_vector_type(8)));
typedef _Float16 f16x4 __attribute__((ext_vector_type(4)));
typedef float   floatx4 __attribute__((ext_vector_type(4)));

#define MFMA16(a, b, c) __builtin_amdgcn_mfma_f32_16x16x32_f16((a), (b), (c), 0, 0, 0)

// ---------------- fp32 -> fp16 convert (vectorized, exact-size grids) ------
__global__ __launch_bounds__(256) void cvt_f32_f16(const float* __restrict__ src,
                                                   f16_t* __restrict__ dst, int n) {
  int i = (blockIdx.x * 256 + threadIdx.x) * 4;
  if (i < n) {
    floatx4 v = *(const floatx4*)(src + i);
    f16x4 o;
    o.x = (_Float16)v.x; o.y = (_Float16)v.y; o.z = (_Float16)v.z; o.w = (_Float16)v.w;
    *(f16x4*)(dst + i) = o;
  }
}

// ---------------- fused QKV projection: C = x @ W^T, scatter to heads ------
// A = x [4096,1024] f16 row-major, B = w [1024,1024] f16 row-major (n,k).
// grid (64 mtiles, 48 ntiles); ntile/16 selects w_q/w_k/w_v.
// Output layout: q/k/v [B=2][H=16][S=2048][DK=64] f16.
__global__ __launch_bounds__(256) void qkv_gemm(
    const f16_t* __restrict__ xb,
    const f16_t* __restrict__ wqb, const f16_t* __restrict__ wkb,
    const f16_t* __restrict__ wvb,
    f16_t* __restrict__ qb, f16_t* __restrict__ kb, f16_t* __restrict__ vb) {
  __shared__ f16_t As[64][72];  // +8 pad: row stride 144B -> 4-bank rotation
  __shared__ f16_t Bs[64][72];
  const int t = threadIdx.x;
  const int w = t >> 6, lane = t & 63, quad = lane >> 4, col = lane & 15;
  const int mbase = blockIdx.x * 64;
  const int nt = blockIdx.y;
  const int which = nt >> 4;
  const int ncol0 = (nt & 15) * 64;
  const f16_t* wsel = (which == 0) ? wqb : (which == 1) ? wkb : wvb;
  f16_t* osel = (which == 0) ? qb : (which == 1) ? kb : vb;

  floatx4 zero4 = {0.f, 0.f, 0.f, 0.f};
  floatx4 acc[4];
  acc[0] = acc[1] = acc[2] = acc[3] = zero4;

  for (int kt = 0; kt < 16; ++kt) {
    const int k0 = kt * 64;
#pragma unroll
    for (int rep = 0; rep < 2; ++rep) {
      int cid = t + rep * 256;            // 0..511
      int r = cid >> 3, c = (cid & 7) * 8;
      *(f16x8*)&As[r][c] = *(const f16x8*)(xb + (size_t)(mbase + r) * 1024 + k0 + c);
      *(f16x8*)&Bs[r][c] = *(const f16x8*)(wsel + (size_t)(ncol0 + r) * 1024 + k0 + c);
    }
    __syncthreads();
#pragma unroll
    for (int ch = 0; ch < 2; ++ch) {
      f16x8 a = *(const f16x8*)&As[w * 16 + col][ch * 32 + quad * 8];
#pragma unroll
      for (int cb = 0; cb < 4; ++cb) {
        f16x8 b = *(const f16x8*)&Bs[cb * 16 + col][ch * 32 + quad * 8];
        acc[cb] = MFMA16(a, b, acc[cb]);
      }
    }
    __syncthreads();
  }
  // epilogue: C row = quad*4+i, col = lane&15 (m89-verified layout)
#pragma unroll
  for (int cb = 0; cb < 4; ++cb) {
#pragma unroll
    for (int i = 0; i < 4; ++i) {
      int m = mbase + w * 16 + quad * 4 + i;   // token index b*2048+s
      int nf = ncol0 + cb * 16 + col;          // feature 0..1023
      int h = nf >> 6, d = nf & 63;
      int bb = m >> 11, s = m & 2047;
      osel[(size_t)(((bb * 16 + h) * 2048) + s) * 64 + d] = (f16_t)acc[cb][i];
    }
  }
}

// ---------------- output projection: out = ctx @ w_o^T (fp32 out) ----------
__global__ __launch_bounds__(256) void out_gemm(
    const f16_t* __restrict__ ab, const f16_t* __restrict__ wob,
    float* __restrict__ outp) {
  __shared__ f16_t As[64][72];
  __shared__ f16_t Bs[64][72];
  const int t = threadIdx.x;
  const int w = t >> 6, lane = t & 63, quad = lane >> 4, col = lane & 15;
  const int mbase = blockIdx.x * 64;
  const int nbase = blockIdx.y * 64;

  floatx4 zero4 = {0.f, 0.f, 0.f, 0.f};
  floatx4 acc[4];
  acc[0] = acc[1] = acc[2] = acc[3] = zero4;

  for (int kt = 0; kt < 16; ++kt) {
    const int k0 = kt * 64;
#pragma unroll
    for (int rep = 0; rep < 2; ++rep) {
      int cid = t + rep * 256;
      int r = cid >> 3, c = (cid & 7) * 8;
      *(f16x8*)&As[r][c] = *(const f16x8*)(ab + (size_t)(mbase + r) * 1024 + k0 + c);
      *(f16x8*)&Bs[r][c] = *(const f16x8*)(wob + (size_t)(nbase + r) * 1024 + k0 + c);
    }
    __syncthreads();
#pragma unroll
    for (int ch = 0; ch < 2; ++ch) {
      f16x8 a = *(const f16x8*)&As[w * 16 + col][ch * 32 + quad * 8];
#pragma unroll
      for (int cb = 0; cb < 4; ++cb) {
        f16x8 b = *(const f16x8*)&Bs[cb * 16 + col][ch * 32 + quad * 8];
        acc[cb] = MFMA16(a, b, acc[cb]);
      }
    }
    __syncthreads();
  }
#pragma unroll
  for (int cb = 0; cb < 4; ++cb) {
#pragma unroll
    for (int i = 0; i < 4; ++i) {
      int m = mbase + w * 16 + quad * 4 + i;
      int n = nbase + cb * 16 + col;
      outp[(size_t)m * 1024 + n] = acc[cb][i];
    }
  }
}

// ---------------- flash attention with additive bias -----------------------
// grid (32 qtiles, 16 heads), 512 threads = 8 waves.
// waves 0-3: batch 0 (16 q-rows each); waves 4-7: batch 1.
// Bias tile (64q x 64k) staged in LDS once, shared by both batches.
__global__ __launch_bounds__(512) void attn_kernel(
    const f16_t* __restrict__ qb, const f16_t* __restrict__ kb,
    const f16_t* __restrict__ vb, const float* __restrict__ bias,
    f16_t* __restrict__ ctxb) {
  __shared__ f16_t Ks[2][64][72];    // [batch][key][d]
  __shared__ f16_t Vt[2][64][72];    // [batch][d][key]  (V transposed)
  __shared__ f16_t biasS[64][72];    // [q_local][k_local]
  __shared__ f16_t Ps[8][16][72];    // per-wave P round-trip (C->A layout)

  const int t = threadIdx.x;
  const int w = t >> 6, lane = t & 63, quad = lane >> 4, col = lane & 15;
  const int bb = w >> 2, w4 = w & 3;
  const int h = blockIdx.y;
  const int qbase = blockIdx.x * 64;

  // Q fragments for this wave's 16 rows (A layout: m=lane&15, k=quad*8+j)
  f16x8 qf[2];
  {
    const f16_t* qp = qb + (size_t)(((bb * 16 + h) * 2048) + qbase + w4 * 16 + col) * 64;
    qf[0] = *(const f16x8*)(qp + quad * 8);
    qf[1] = *(const f16x8*)(qp + 32 + quad * 8);
  }

  float mprev[4], lrun[4];
  floatx4 zero4 = {0.f, 0.f, 0.f, 0.f};
  floatx4 oacc[4];
#pragma unroll
  for (int i = 0; i < 4; ++i) { mprev[i] = -3e38f; lrun[i] = 0.f; }
  oacc[0] = oacc[1] = oacc[2] = oacc[3] = zero4;

  for (int kt = 0; kt < 32; ++kt) {
    const int kbase = kt * 64;
    // ---- stage K tiles (both batches) ----
#pragma unroll
    for (int rep = 0; rep < 2; ++rep) {
      int cid = t + rep * 512;                   // 0..1023
      int b2 = cid >> 9, rem = cid & 511;
      int r = rem >> 3, c = (rem & 7) * 8;
      *(f16x8*)&Ks[b2][r][c] =
          *(const f16x8*)(kb + (size_t)(((b2 * 16 + h) * 2048) + kbase + r) * 64 + c);
    }
    // ---- stage V transposed (threads 0..255; 4k x 8d sub-blocks) ----
    if (t < 256) {
      int b2 = t >> 7, rem = t & 127;
      int kk0 = (rem & 15) * 4, d0 = (rem >> 4) * 8;
      f16x8 rows[4];
#pragma unroll
      for (int j = 0; j < 4; ++j)
        rows[j] = *(const f16x8*)(vb +
            (size_t)(((b2 * 16 + h) * 2048) + kbase + kk0 + j) * 64 + d0);
#pragma unroll
      for (int d = 0; d < 8; ++d) {
        f16x4 pk;
        pk.x = rows[0][d]; pk.y = rows[1][d]; pk.z = rows[2][d]; pk.w = rows[3][d];
        *(f16x4*)&Vt[b2][d0 + d][kk0] = pk;      // 8B packed write
      }
    }
    // ---- stage bias tile (fp32 global -> f16 LDS), read ONCE from HBM ----
    {
      int r = t >> 3, c0 = (t & 7) * 8;
      const float* bp = bias + ((size_t)h * 2048 + qbase + r) * 2048 + kbase + c0;
      floatx4 v0 = *(const floatx4*)bp;
      floatx4 v1 = *(const floatx4*)(bp + 4);
      f16x8 bo;
      bo[0] = (_Float16)v0.x; bo[1] = (_Float16)v0.y;
      bo[2] = (_Float16)v0.z; bo[3] = (_Float16)v0.w;
      bo[4] = (_Float16)v1.x; bo[5] = (_Float16)v1.y;
      bo[6] = (_Float16)v1.z; bo[7] = (_Float16)v1.w;
      *(f16x8*)&biasS[r][c0] = bo;
    }
    __syncthreads();

    // ---- scores: S = Q K^T  (16q x 64k per wave) ----
    floatx4 sacc[4];
    sacc[0] = sacc[1] = sacc[2] = sacc[3] = zero4;
#pragma unroll
    for (int ch = 0; ch < 2; ++ch) {
#pragma unroll
      for (int cb = 0; cb < 4; ++cb) {
        f16x8 kf = *(const f16x8*)&Ks[bb][cb * 16 + col][ch * 32 + quad * 8];
        sacc[cb] = MFMA16(qf[ch], kf, sacc[cb]);
      }
    }
    // ---- bias add (C layout: row=quad*4+i, col=lane&15) ----
    float sv[4][4];
#pragma unroll
    for (int cb = 0; cb < 4; ++cb)
#pragma unroll
      for (int i = 0; i < 4; ++i)
        sv[cb][i] = sacc[cb][i] +
                    (float)biasS[w4 * 16 + quad * 4 + i][cb * 16 + col];

    // ---- online softmax (row groups live in 16 lanes of each quad) ----
    float alpha[4];
#pragma unroll
    for (int i = 0; i < 4; ++i) {
      float rm = fmaxf(fmaxf(sv[0][i], sv[1][i]), fmaxf(sv[2][i], sv[3][i]));
#pragma unroll
      for (int msk = 1; msk < 16; msk <<= 1)
        rm = fmaxf(rm, __shfl_xor(rm, msk, 64));
      float mnew = fmaxf(mprev[i], rm);
      alpha[i] = __expf(mprev[i] - mnew);
      float rs = 0.f;
#pragma unroll
      for (int cb = 0; cb < 4; ++cb) {
        float p = __expf(sv[cb][i] - mnew);
        sv[cb][i] = p;
        rs += p;
      }
#pragma unroll
      for (int msk = 1; msk < 16; msk <<= 1)
        rs += __shfl_xor(rs, msk, 64);
      lrun[i] = lrun[i] * alpha[i] + rs;
      mprev[i] = mnew;
    }
    // ---- write P (C layout) to LDS, rescale O ----
#pragma unroll
    for (int cb = 0; cb < 4; ++cb)
#pragma unroll
      for (int i = 0; i < 4; ++i)
        Ps[w][quad * 4 + i][cb * 16 + col] = (f16_t)sv[cb][i];
#pragma unroll
    for (int db = 0; db < 4; ++db) {
      oacc[db].x *= alpha[0]; oacc[db].y *= alpha[1];
      oacc[db].z *= alpha[2]; oacc[db].w *= alpha[3];
    }
    // ---- O += P V  (P re-read in A layout; V from transposed tile) ----
#pragma unroll
    for (int ch = 0; ch < 2; ++ch) {
      f16x8 pf = *(const f16x8*)&Ps[w][col][ch * 32 + quad * 8];
#pragma unroll
      for (int db = 0; db < 4; ++db) {
        f16x8 vf = *(const f16x8*)&Vt[bb][db * 16 + col][ch * 32 + quad * 8];
        oacc[db] = MFMA16(pf, vf, oacc[db]);
      }
    }
    __syncthreads();
  }

  // ---- epilogue: ctx merged [4096][1024] f16 ----
#pragma unroll
  for (int db = 0; db < 4; ++db)
#pragma unroll
    for (int i = 0; i < 4; ++i) {
      int m = bb * 2048 + qbase + w4 * 16 + quad * 4 + i;
      int n = h * 64 + db * 16 + col;
      ctxb[(size_t)m * 1024 + n] = (f16_t)(oacc[db][i] / lrun[i]);
    }
}

// ---------------------------------------------------------------------------
extern "C" void kernel_launch(void* const* d_in, const int* in_sizes, int n_in,
                              void* d_out, int out_size, void* d_ws, size_t ws_size,
                              hipStream_t stream) {
  const float* x    = (const float*)d_in[0];
  const float* bias = (const float*)d_in[1];
  const float* wq   = (const float*)d_in[2];
  const float* wk   = (const float*)d_in[3];
  const float* wv   = (const float*)d_in[4];
  const float* wo   = (const float*)d_in[5];
  float* outp = (float*)d_out;
  char* ws = (char*)d_ws;
  const size_t MB = 1u << 20;

  f16_t* xb   = (f16_t*)(ws);             //  8 MB  x as f16 [4096,1024]
  f16_t* wqb  = (f16_t*)(ws + 8 * MB);    //  2 MB
  f16_t* wkb  = (f16_t*)(ws + 10 * MB);   //  2 MB
  f16_t* wvb  = (f16_t*)(ws + 12 * MB);   //  2 MB
  f16_t* wob  = (f16_t*)(ws + 14 * MB);   //  2 MB
  f16_t* qb   = (f16_t*)(ws + 16 * MB);   //  8 MB  [2,16,2048,64]
  f16_t* kb   = (f16_t*)(ws + 24 * MB);   //  8 MB
  f16_t* vb   = (f16_t*)(ws + 32 * MB);   //  8 MB
  f16_t* ctxb = (f16_t*)(ws + 40 * MB);   //  8 MB  merged ctx [4096,1024]
  // total 48 MB of d_ws

  cvt_f32_f16<<<4096, 256, 0, stream>>>(x, xb, 4194304);
  cvt_f32_f16<<<1024, 256, 0, stream>>>(wq, wqb, 1048576);
  cvt_f32_f16<<<1024, 256, 0, stream>>>(wk, wkb, 1048576);
  cvt_f32_f16<<<1024, 256, 0, stream>>>(wv, wvb, 1048576);
  cvt_f32_f16<<<1024, 256, 0, stream>>>(wo, wob, 1048576);

  qkv_gemm<<<dim3(64, 48), 256, 0, stream>>>(xb, wqb, wkb, wvb, qb, kb, vb);
  attn_kernel<<<dim3(32, 16), 512, 0, stream>>>(qb, kb, vb, bias, ctxb);
  out_gemm<<<dim3(64, 16), 256, 0, stream>>>(ctxb, wob, outp);
}

// Round 3
// 506.816 us; speedup vs baseline: 1.0722x; 1.0722x over previous
//
#include <hip/hip_runtime.h>

// ---------------------------------------------------------------------------
// T5-style self-attention, MI355X (gfx950), fp16 MFMA internal precision.
// B=2, S=2048, H=16, DK=64, D_MODEL=1024.
// R3 = R2 with the K=16 MFMA intrinsic spelled correctly
// (__builtin_amdgcn_mfma_f32_16x16x16f16 — legacy shapes have no final '_').
// ---------------------------------------------------------------------------

typedef _Float16 f16_t;
typedef _Float16 f16x8 __attribute__((ext_vector_type(8)));
typedef _Float16 f16x4 __attribute__((ext_vector_type(4)));
typedef float   floatx4 __attribute__((ext_vector_type(4)));

#define MFMA16(a, b, c)    __builtin_amdgcn_mfma_f32_16x16x32_f16((a), (b), (c), 0, 0, 0)
#define MFMA16K16(a, b, c) __builtin_amdgcn_mfma_f32_16x16x16f16((a), (b), (c), 0, 0, 0)

// ---------------- fp32 -> fp16 convert -------------------------------------
__global__ __launch_bounds__(256) void cvt_f32_f16(const float* __restrict__ src,
                                                   f16_t* __restrict__ dst, int n) {
  int i = (blockIdx.x * 256 + threadIdx.x) * 4;
  if (i < n) {
    floatx4 v = *(const floatx4*)(src + i);
    f16x4 o;
    o.x = (_Float16)v.x; o.y = (_Float16)v.y; o.z = (_Float16)v.z; o.w = (_Float16)v.w;
    *(f16x4*)(dst + i) = o;
  }
}

// ---------------- fused QKV projection: 128x128 tile -----------------------
// A = x [4096,1024] f16, B = w [1024,1024] f16 (row-major [n][k]).
// grid (32, 24); by>>3 selects w_q/w_k/w_v; (by&7)*128 = feature base.
// Output: q/k/v [B=2][H=16][S=2048][DK=64] f16.
__global__ __launch_bounds__(256) void qkv_gemm(
    const f16_t* __restrict__ xb,
    const f16_t* __restrict__ wqb, const f16_t* __restrict__ wkb,
    const f16_t* __restrict__ wvb,
    f16_t* __restrict__ qb, f16_t* __restrict__ kb, f16_t* __restrict__ vb) {
  __shared__ f16_t As[128][72];
  __shared__ f16_t Bs[128][72];
  const int t = threadIdx.x;
  const int w = t >> 6, lane = t & 63, quad = lane >> 4, col = lane & 15;
  const int wm = w & 1, wn = w >> 1;
  const int mbase = blockIdx.x * 128;
  const int which = blockIdx.y >> 3;
  const int ncol0 = (blockIdx.y & 7) * 128;
  const f16_t* wsel = (which == 0) ? wqb : (which == 1) ? wkb : wvb;
  f16_t* osel = (which == 0) ? qb : (which == 1) ? kb : vb;

  floatx4 zero4 = {0.f, 0.f, 0.f, 0.f};
  floatx4 acc[4][4];
#pragma unroll
  for (int i = 0; i < 4; ++i)
#pragma unroll
    for (int j = 0; j < 4; ++j) acc[i][j] = zero4;

  for (int kt = 0; kt < 16; ++kt) {
    const int k0 = kt * 64;
#pragma unroll
    for (int rep = 0; rep < 4; ++rep) {
      int cid = t + rep * 256;            // 0..1023
      int r = cid >> 3, c = (cid & 7) * 8;
      *(f16x8*)&As[r][c] = *(const f16x8*)(xb + (size_t)(mbase + r) * 1024 + k0 + c);
      *(f16x8*)&Bs[r][c] = *(const f16x8*)(wsel + (size_t)(ncol0 + r) * 1024 + k0 + c);
    }
    __syncthreads();
#pragma unroll
    for (int ch = 0; ch < 2; ++ch) {
      f16x8 a[4], b[4];
#pragma unroll
      for (int i = 0; i < 4; ++i)
        a[i] = *(const f16x8*)&As[wm * 64 + i * 16 + col][ch * 32 + quad * 8];
#pragma unroll
      for (int j = 0; j < 4; ++j)
        b[j] = *(const f16x8*)&Bs[wn * 64 + j * 16 + col][ch * 32 + quad * 8];
#pragma unroll
      for (int i = 0; i < 4; ++i)
#pragma unroll
        for (int j = 0; j < 4; ++j)
          acc[i][j] = MFMA16(a[i], b[j], acc[i][j]);
    }
    __syncthreads();
  }
  // epilogue: C row=quad*4+rr (M), col=lane&15 (N); scatter to head layout
#pragma unroll
  for (int i = 0; i < 4; ++i)
#pragma unroll
    for (int j = 0; j < 4; ++j)
#pragma unroll
      for (int rr = 0; rr < 4; ++rr) {
        int m = mbase + wm * 64 + i * 16 + quad * 4 + rr;  // token b*2048+s
        int nf = ncol0 + wn * 64 + j * 16 + col;           // feature 0..1023
        int h = nf >> 6, d = nf & 63;
        int bb2 = m >> 11, s = m & 2047;
        osel[(size_t)(((bb2 * 16 + h) * 2048) + s) * 64 + d] = (f16_t)acc[i][j][rr];
      }
}

// ---------------- output projection: 128x128 tile, fp32 out ----------------
__global__ __launch_bounds__(256) void out_gemm(
    const f16_t* __restrict__ ab, const f16_t* __restrict__ wob,
    float* __restrict__ outp) {
  __shared__ f16_t As[128][72];
  __shared__ f16_t Bs[128][72];
  const int t = threadIdx.x;
  const int w = t >> 6, lane = t & 63, quad = lane >> 4, col = lane & 15;
  const int wm = w & 1, wn = w >> 1;
  const int mbase = blockIdx.x * 128;
  const int nbase = blockIdx.y * 128;

  floatx4 zero4 = {0.f, 0.f, 0.f, 0.f};
  floatx4 acc[4][4];
#pragma unroll
  for (int i = 0; i < 4; ++i)
#pragma unroll
    for (int j = 0; j < 4; ++j) acc[i][j] = zero4;

  for (int kt = 0; kt < 16; ++kt) {
    const int k0 = kt * 64;
#pragma unroll
    for (int rep = 0; rep < 4; ++rep) {
      int cid = t + rep * 256;
      int r = cid >> 3, c = (cid & 7) * 8;
      *(f16x8*)&As[r][c] = *(const f16x8*)(ab + (size_t)(mbase + r) * 1024 + k0 + c);
      *(f16x8*)&Bs[r][c] = *(const f16x8*)(wob + (size_t)(nbase + r) * 1024 + k0 + c);
    }
    __syncthreads();
#pragma unroll
    for (int ch = 0; ch < 2; ++ch) {
      f16x8 a[4], b[4];
#pragma unroll
      for (int i = 0; i < 4; ++i)
        a[i] = *(const f16x8*)&As[wm * 64 + i * 16 + col][ch * 32 + quad * 8];
#pragma unroll
      for (int j = 0; j < 4; ++j)
        b[j] = *(const f16x8*)&Bs[wn * 64 + j * 16 + col][ch * 32 + quad * 8];
#pragma unroll
      for (int i = 0; i < 4; ++i)
#pragma unroll
        for (int j = 0; j < 4; ++j)
          acc[i][j] = MFMA16(a[i], b[j], acc[i][j]);
    }
    __syncthreads();
  }
#pragma unroll
  for (int i = 0; i < 4; ++i)
#pragma unroll
    for (int j = 0; j < 4; ++j)
#pragma unroll
      for (int rr = 0; rr < 4; ++rr) {
        int m = mbase + wm * 64 + i * 16 + quad * 4 + rr;
        int n = nbase + wn * 64 + j * 16 + col;
        outp[(size_t)m * 1024 + n] = acc[i][j][rr];
      }
}

// ---------------- flash attention, S^T formulation -------------------------
// grid (32 qtiles, 16 heads), 512 threads = 8 waves.
// waves 0-3: batch 0; waves 4-7: batch 1. Bias tile staged once, shared.
// S^T = K Q^T via MFMA(kf, qf): C row=key(quad*4+i), col=q(lane&15).
// Each lane owns ONE q-row's softmax state -> no per-iter cross-lane
// reductions except 2 shfl_xor (quads) + 4 alpha broadcasts.
// P (q=lane&15, key=quad*4+i) is EXACTLY the 16x16x16 A-operand layout:
// no LDS round-trip for P.
__global__ __launch_bounds__(512) void attn_kernel(
    const f16_t* __restrict__ qb, const f16_t* __restrict__ kb,
    const f16_t* __restrict__ vb, const float* __restrict__ bias,
    f16_t* __restrict__ ctxb) {
  __shared__ f16_t Ks[2][64][72];    // [batch][key][d]       (36.9 KB)
  __shared__ f16_t Vt[2][64][76];    // [batch][d][key] pad76 (19.5 KB)
  __shared__ f16_t biasS[64][72];    // [q_local][k_local]    ( 9.2 KB)

  const int t = threadIdx.x;
  const int w = t >> 6, lane = t & 63, quad = lane >> 4, col = lane & 15;
  const int bb = w >> 2, w4 = w & 3;
  const int h = blockIdx.y;
  const int qbase = blockIdx.x * 64;

  // Q fragments (B-operand: n=lane&15=q, k=quad*8+j=d)
  f16x8 qf[2];
  {
    const f16_t* qp = qb + (size_t)(((bb * 16 + h) * 2048) + qbase + w4 * 16 + col) * 64;
    qf[0] = *(const f16x8*)(qp + quad * 8);
    qf[1] = *(const f16x8*)(qp + 32 + quad * 8);
  }

  float mprev = -3e38f, lrun = 0.f;   // per-lane: row q = w4*16 + col
  floatx4 zero4 = {0.f, 0.f, 0.f, 0.f};
  floatx4 oacc[4];
  oacc[0] = oacc[1] = oacc[2] = oacc[3] = zero4;

  for (int kt = 0; kt < 32; ++kt) {
    const int kbase = kt * 64;
    // ---- stage K tiles (both batches) ----
#pragma unroll
    for (int rep = 0; rep < 2; ++rep) {
      int cid = t + rep * 512;                   // 0..1023
      int b2 = cid >> 9, rem = cid & 511;
      int r = rem >> 3, c = (rem & 7) * 8;
      *(f16x8*)&Ks[b2][r][c] =
          *(const f16x8*)(kb + (size_t)(((b2 * 16 + h) * 2048) + kbase + r) * 64 + c);
    }
    // ---- stage V transposed (threads 0..255) ----
    if (t < 256) {
      int b2 = t >> 7, rem = t & 127;
      int kk0 = (rem & 15) * 4, d0 = (rem >> 4) * 8;
      f16x8 rows[4];
#pragma unroll
      for (int j = 0; j < 4; ++j)
        rows[j] = *(const f16x8*)(vb +
            (size_t)(((b2 * 16 + h) * 2048) + kbase + kk0 + j) * 64 + d0);
#pragma unroll
      for (int d = 0; d < 8; ++d) {
        f16x4 pk;
        pk.x = rows[0][d]; pk.y = rows[1][d]; pk.z = rows[2][d]; pk.w = rows[3][d];
        *(f16x4*)&Vt[b2][d0 + d][kk0] = pk;
      }
    }
    // ---- stage bias tile (fp32 -> f16 LDS), read once from HBM ----
    {
      int r = t >> 3, c0 = (t & 7) * 8;
      const float* bp = bias + ((size_t)h * 2048 + qbase + r) * 2048 + kbase + c0;
      floatx4 v0 = *(const floatx4*)bp;
      floatx4 v1 = *(const floatx4*)(bp + 4);
      f16x8 bo;
      bo[0] = (_Float16)v0.x; bo[1] = (_Float16)v0.y;
      bo[2] = (_Float16)v0.z; bo[3] = (_Float16)v0.w;
      bo[4] = (_Float16)v1.x; bo[5] = (_Float16)v1.y;
      bo[6] = (_Float16)v1.z; bo[7] = (_Float16)v1.w;
      *(f16x8*)&biasS[r][c0] = bo;
    }
    __syncthreads();

    // ---- S^T = K Q^T : 16 keys per cb tile, this wave's 16 q-rows ----
    floatx4 sacc[4];
    sacc[0] = sacc[1] = sacc[2] = sacc[3] = zero4;
#pragma unroll
    for (int ch = 0; ch < 2; ++ch) {
#pragma unroll
      for (int cb = 0; cb < 4; ++cb) {
        f16x8 kf = *(const f16x8*)&Ks[bb][cb * 16 + col][ch * 32 + quad * 8];
        sacc[cb] = MFMA16(kf, qf[ch], sacc[cb]);
      }
    }
    // ---- bias add: lane's q-row = w4*16+col, keys cb*16+quad*4+i ----
    float sv[4][4];
#pragma unroll
    for (int cb = 0; cb < 4; ++cb) {
      f16x4 b4 = *(const f16x4*)&biasS[w4 * 16 + col][cb * 16 + quad * 4];
#pragma unroll
      for (int i = 0; i < 4; ++i)
        sv[cb][i] = sacc[cb][i] + (float)b4[i];
    }
    // ---- per-lane softmax over 16 keys; cross-quad reduce (2 shfl) ----
    float rm = -3e38f;
#pragma unroll
    for (int cb = 0; cb < 4; ++cb)
#pragma unroll
      for (int i = 0; i < 4; ++i) rm = fmaxf(rm, sv[cb][i]);
    rm = fmaxf(rm, __shfl_xor(rm, 16, 64));
    rm = fmaxf(rm, __shfl_xor(rm, 32, 64));
    float mnew = fmaxf(mprev, rm);
    float alpha = __expf(mprev - mnew);
    mprev = mnew;
    float ls = 0.f;
#pragma unroll
    for (int cb = 0; cb < 4; ++cb)
#pragma unroll
      for (int i = 0; i < 4; ++i) {
        float p = __expf(sv[cb][i] - mnew);
        sv[cb][i] = p;
        ls += p;
      }
    lrun = lrun * alpha + ls;
    // ---- rescale O: alpha for O-rows quad*4+i (4 broadcasts) ----
    float a0 = __shfl(alpha, quad * 4 + 0, 64);
    float a1 = __shfl(alpha, quad * 4 + 1, 64);
    float a2 = __shfl(alpha, quad * 4 + 2, 64);
    float a3 = __shfl(alpha, quad * 4 + 3, 64);
#pragma unroll
    for (int db = 0; db < 4; ++db) {
      oacc[db].x *= a0; oacc[db].y *= a1; oacc[db].z *= a2; oacc[db].w *= a3;
    }
    // ---- O += P V : P direct from regs (A-operand), V from Vt (B) ----
#pragma unroll
    for (int cb = 0; cb < 4; ++cb) {
      f16x4 pf;
      pf[0] = (_Float16)sv[cb][0]; pf[1] = (_Float16)sv[cb][1];
      pf[2] = (_Float16)sv[cb][2]; pf[3] = (_Float16)sv[cb][3];
#pragma unroll
      for (int db = 0; db < 4; ++db) {
        f16x4 vf = *(const f16x4*)&Vt[bb][db * 16 + col][cb * 16 + quad * 4];
        oacc[db] = MFMA16K16(pf, vf, oacc[db]);
      }
    }
    __syncthreads();
  }

  // ---- finalize: total row sums (2 shfl), then divide & store ----
  float lt = lrun;
  lt += __shfl_xor(lt, 16, 64);
  lt += __shfl_xor(lt, 32, 64);
  float linv[4];
#pragma unroll
  for (int i = 0; i < 4; ++i)
    linv[i] = 1.0f / __shfl(lt, quad * 4 + i, 64);
#pragma unroll
  for (int db = 0; db < 4; ++db)
#pragma unroll
    for (int i = 0; i < 4; ++i) {
      int m = bb * 2048 + qbase + w4 * 16 + quad * 4 + i;
      int n = h * 64 + db * 16 + col;
      ctxb[(size_t)m * 1024 + n] = (f16_t)(oacc[db][i] * linv[i]);
    }
}

// ---------------------------------------------------------------------------
extern "C" void kernel_launch(void* const* d_in, const int* in_sizes, int n_in,
                              void* d_out, int out_size, void* d_ws, size_t ws_size,
                              hipStream_t stream) {
  const float* x    = (const float*)d_in[0];
  const float* bias = (const float*)d_in[1];
  const float* wq   = (const float*)d_in[2];
  const float* wk   = (const float*)d_in[3];
  const float* wv   = (const float*)d_in[4];
  const float* wo   = (const float*)d_in[5];
  float* outp = (float*)d_out;
  char* ws = (char*)d_ws;
  const size_t MB = 1u << 20;

  f16_t* xb   = (f16_t*)(ws);             //  8 MB
  f16_t* wqb  = (f16_t*)(ws + 8 * MB);    //  2 MB
  f16_t* wkb  = (f16_t*)(ws + 10 * MB);   //  2 MB
  f16_t* wvb  = (f16_t*)(ws + 12 * MB);   //  2 MB
  f16_t* wob  = (f16_t*)(ws + 14 * MB);   //  2 MB
  f16_t* qb   = (f16_t*)(ws + 16 * MB);   //  8 MB [2,16,2048,64]
  f16_t* kb   = (f16_t*)(ws + 24 * MB);   //  8 MB
  f16_t* vb   = (f16_t*)(ws + 32 * MB);   //  8 MB
  f16_t* ctxb = (f16_t*)(ws + 40 * MB);   //  8 MB [4096,1024]

  cvt_f32_f16<<<4096, 256, 0, stream>>>(x, xb, 4194304);
  cvt_f32_f16<<<1024, 256, 0, stream>>>(wq, wqb, 1048576);
  cvt_f32_f16<<<1024, 256, 0, stream>>>(wk, wkb, 1048576);
  cvt_f32_f16<<<1024, 256, 0, stream>>>(wv, wvb, 1048576);
  cvt_f32_f16<<<1024, 256, 0, stream>>>(wo, wob, 1048576);

  qkv_gemm<<<dim3(32, 24), 256, 0, stream>>>(xb, wqb, wkb, wvb, qb, kb, vb);
  attn_kernel<<<dim3(32, 16), 512, 0, stream>>>(qb, kb, vb, bias, ctxb);
  out_gemm<<<dim3(32, 8), 256, 0, stream>>>(ctxb, wob, outp);
}